// Round 11
// baseline (683.764 us; speedup 1.0000x reference)
//
#include <hip/hip_runtime.h>
#include <hip/hip_bf16.h>
#include <stdint.h>

#define T_TOK 2048
#define HDIM  1024
#define IDIM  768
#define NEXP  32
#define TOPK  4
#define NPAIR (T_TOK*TOPK)   // 8192

typedef __attribute__((ext_vector_type(8))) short bf16x8;
typedef __attribute__((ext_vector_type(4))) float f32x4;

__device__ __forceinline__ unsigned short f2bf(float f){
  union { float f; unsigned u; } v; v.f = f;
  unsigned r = (v.u + 0x7fffu + ((v.u >> 16) & 1u)) >> 16;  // RNE
  return (unsigned short)r;
}

__device__ __forceinline__ unsigned pack_bf2(float lo, float hi){
  __hip_bfloat162 h2 = __float22bfloat162_rn(float2{lo, hi});  // v_cvt_pk_bf16_f32
  union { __hip_bfloat162 h; unsigned u; } v; v.h = h2;
  return v.u;
}

__device__ __forceinline__ float bf2f(unsigned short s){
  union { unsigned u; float f; } v; v.u = ((unsigned)s) << 16;
  return v.f;
}

// ---------------- x fp32 -> bf16 ----------------
__global__ __launch_bounds__(256) void k_convert_x(const float* __restrict__ x,
                                                   ushort* __restrict__ xb){
  int idx = blockIdx.x*256 + threadIdx.x;
  float4 v = ((const float4*)x)[idx];
  ushort4 o; o.x=f2bf(v.x); o.y=f2bf(v.y); o.z=f2bf(v.z); o.w=f2bf(v.w);
  ((ushort4*)xb)[idx] = o;
}

// ---------------- router ----------------
__global__ __launch_bounds__(256) void k_router(const float* __restrict__ x,
                                                const float* __restrict__ gw,
                                                int* __restrict__ ei, float* __restrict__ wv,
                                                int* __restrict__ counts){
  int wid  = threadIdx.x >> 6;
  int lane = threadIdx.x & 63;
  int t = blockIdx.x*4 + wid;
  float xv[16];
  #pragma unroll
  for (int i=0;i<16;i++) xv[i] = x[t*HDIM + i*64 + lane];
  float p[NEXP];
  #pragma unroll
  for (int e=0;e<NEXP;e++){
    const float* w = gw + e*HDIM;
    float a = 0.f;
    #pragma unroll
    for (int i=0;i<16;i++) a = fmaf(xv[i], w[i*64+lane], a);
    #pragma unroll
    for (int off=32; off>=1; off>>=1) a += __shfl_xor(a, off, 64);
    p[e] = a;
  }
  float m = p[0];
  #pragma unroll
  for (int e=1;e<NEXP;e++) m = fmaxf(m, p[e]);
  #pragma unroll
  for (int e=0;e<NEXP;e++) p[e] = __expf(p[e]-m);
  unsigned used = 0; int sel[TOPK]; float sw[TOPK]; float wsum = 0.f;
  #pragma unroll
  for (int k=0;k<TOPK;k++){
    float best = -1.f; int bi = 0;
    #pragma unroll
    for (int e=0;e<NEXP;e++){
      bool ok = (((used>>e)&1u)==0u) && (p[e] > best);
      best = ok ? p[e] : best; bi = ok ? e : bi;
    }
    used |= 1u<<bi; sel[k]=bi; sw[k]=best; wsum += best;
  }
  if (lane==0){
    float inv = 1.f/wsum;
    #pragma unroll
    for (int k=0;k<TOPK;k++){
      ei[t*TOPK+k] = sel[k];
      wv[t*TOPK+k] = sw[k]*inv;
      atomicAdd(&counts[sel[k]], 1);
    }
  }
}

// ---------------- offsets ----------------
__global__ void k_offsets(const int* __restrict__ counts, int* __restrict__ offsets){
  if (threadIdx.x==0 && blockIdx.x==0){
    int s=0;
    for (int e=0;e<NEXP;e++){ offsets[e]=s; s+=counts[e]; }
    offsets[NEXP]=s;
  }
}

__global__ __launch_bounds__(256) void k_scatter(const int* __restrict__ ei,
                                                 const int* __restrict__ offsets,
                                                 int* __restrict__ cursor,
                                                 int* __restrict__ slot_tk,
                                                 int* __restrict__ tk_slot){
  int g = blockIdx.x*256 + threadIdx.x;
  int e = ei[g];
  int pos = atomicAdd(&cursor[e], 1);
  int slot = offsets[e] + pos;
  slot_tk[slot] = g;
  tk_slot[g] = slot;
}

// ---------------- gate/up GEMM (one mat per block, raw output) ----------------
// Block = (expert, mat, 32 i-rows). Stage: each wave reads 4 FULL weight rows
// contiguously (lane-stride-32B windows, back-to-back), cvt_pk -> bf16 LDS tile
// with chunk-XOR swizzle. ONE barrier. Consume: A direct from L2 (xb), B via
// single ds_read_b128, M=128 per pass, dynamic passes over ne.
__global__ __launch_bounds__(512,4) void k_gateup(const ushort* __restrict__ xb,
    const float* __restrict__ w1, const float* __restrict__ w3,
    const int* __restrict__ offsets, const int* __restrict__ slot_tk,
    ushort* __restrict__ gbuf, ushort* __restrict__ ubuf){
  int bi  = blockIdx.x;                   // 1536
  int j   = bi >> 3;                      // 0..191
  int e   = (bi & 7) + 8*(j/48);
  int rest= j % 48;
  int mat = rest / 24;
  int it  = rest % 24;
  int off0 = offsets[e], ne = offsets[e+1]-off0;
  if (ne == 0) return;
  int ibase = it*32;

  __shared__ ushort B[32][1024];          // bf16, 16B-chunk XOR swizzled per row

  int tid = threadIdx.x, wid = tid>>6, lane = tid&63;

  // ---- stage: wave w -> rows [4w, 4w+4) ----
  {
    const float* wsrc = (mat ? w3 : w1) + (size_t)e*IDIM*HDIM + (size_t)ibase*HDIM;
    float4 st[4][4];
    #pragma unroll
    for (int r=0;r<4;r++){
      const char* rp = (const char*)(wsrc + (size_t)(wid*4 + r)*HDIM);
      st[r][0] = *(const float4*)(rp + lane*32);
      st[r][1] = *(const float4*)(rp + lane*32 + 16);
      st[r][2] = *(const float4*)(rp + 2048 + lane*32);
      st[r][3] = *(const float4*)(rp + 2048 + lane*32 + 16);
    }
    #pragma unroll
    for (int r=0;r<4;r++){
      int row = wid*4 + r;
      uint4 c0, c1;
      c0.x=pack_bf2(st[r][0].x,st[r][0].y); c0.y=pack_bf2(st[r][0].z,st[r][0].w);
      c0.z=pack_bf2(st[r][1].x,st[r][1].y); c0.w=pack_bf2(st[r][1].z,st[r][1].w);
      c1.x=pack_bf2(st[r][2].x,st[r][2].y); c1.y=pack_bf2(st[r][2].z,st[r][2].w);
      c1.z=pack_bf2(st[r][3].x,st[r][3].y); c1.w=pack_bf2(st[r][3].z,st[r][3].w);
      char* rowb = (char*)&B[row][0];
      *(uint4*)(rowb + ((lane      ) ^ (row&7))*16) = c0;   // logical chunk = lane
      *(uint4*)(rowb + ((lane + 64 ) ^ (row&7))*16) = c1;   // logical chunk = lane+64
    }
  }
  __syncthreads();

  // ---- consume ----
  ushort* dst = mat ? ubuf : gbuf;
  int q = lane >> 4;
  for (int m0 = 0; m0 < ne; m0 += 128){
    int rowid = m0 + wid*16 + (lane&15);
    int slotc = off0 + (rowid < ne ? rowid : ne-1);
    int tok = slot_tk[slotc] >> 2;
    f32x4 acc0 = {0,0,0,0}, acc1 = {0,0,0,0};
    #pragma unroll
    for (int kh=0; kh<2; kh++){
      bf16x8 a[16];
      const ushort* ap = xb + (size_t)tok*HDIM + kh*512 + q*8;
      #pragma unroll
      for (int s=0;s<16;s++) a[s] = *(const bf16x8*)(ap + s*32);
      #pragma unroll
      for (int s=0;s<16;s++){
        int c = kh*64 + s*4 + q;            // logical 16B chunk
        {
          int row = lane&15;
          bf16x8 b = *(const bf16x8*)((const char*)&B[row][0] + (c ^ (row&7))*16);
          acc0 = __builtin_amdgcn_mfma_f32_16x16x32_bf16(a[s], b, acc0, 0,0,0);
        }
        {
          int row = 16 + (lane&15);
          bf16x8 b = *(const bf16x8*)((const char*)&B[row][0] + (c ^ (row&7))*16);
          acc1 = __builtin_amdgcn_mfma_f32_16x16x32_bf16(a[s], b, acc1, 0,0,0);
        }
      }
    }
    #pragma unroll
    for (int r=0;r<4;r++){
      int row = m0 + wid*16 + q*4 + r;
      if (row < ne){
        size_t base = (size_t)(off0+row)*IDIM + ibase + (lane&15);
        dst[base     ] = f2bf(acc0[r]);
        dst[base + 16] = f2bf(acc1[r]);
      }
    }
  }
}

// ---------------- act = silu(g) * u ----------------
__global__ __launch_bounds__(256) void k_actmul(const ushort* __restrict__ g,
    const ushort* __restrict__ u, ushort* __restrict__ act){
  const int total = NPAIR*IDIM/8;
  int stride = gridDim.x*256;
  for (int i = blockIdx.x*256 + threadIdx.x; i < total; i += stride){
    bf16x8 gv = ((const bf16x8*)g)[i];
    bf16x8 uv = ((const bf16x8*)u)[i];
    bf16x8 ov;
    #pragma unroll
    for (int k=0;k<8;k++){
      float gf = bf2f((unsigned short)gv[k]);
      float uf = bf2f((unsigned short)uv[k]);
      float s  = gf / (1.f + __expf(-gf)) * uf;
      ov[k] = (short)f2bf(s);
    }
    ((bf16x8*)act)[i] = ov;
  }
}

// ---------------- down GEMM ----------------
// Block = (expert, 32 h-rows). Same structure; w2 rows are 3 KB fp32,
// wave's 4 rows = 12 KB contiguous = 6 windows of 2 KB.
__global__ __launch_bounds__(512,4) void k_down(const ushort* __restrict__ act,
    const float* __restrict__ w2, const int* __restrict__ offsets,
    float* __restrict__ pout){
  int bi  = blockIdx.x;                   // 1024
  int e   = (bi & 7) + 8*(bi >> 8);
  int ht  = (bi >> 3) & 31;
  int off0 = offsets[e], ne = offsets[e+1]-off0;
  if (ne == 0) return;
  int hbase = ht*32;

  __shared__ ushort B[32][768];           // bf16 tile, chunk-XOR swizzled

  int tid = threadIdx.x, wid = tid>>6, lane = tid&63;

  // ---- stage: wave w -> rows [4w, 4w+4), 12 KB contiguous ----
  {
    const char* rp = (const char*)(w2 + (size_t)e*HDIM*IDIM + (size_t)(hbase + wid*4)*IDIM);
    float4 st[6][2];
    #pragma unroll
    for (int w2i=0; w2i<6; w2i++){
      st[w2i][0] = *(const float4*)(rp + w2i*2048 + lane*32);
      st[w2i][1] = *(const float4*)(rp + w2i*2048 + lane*32 + 16);
    }
    #pragma unroll
    for (int w2i=0; w2i<6; w2i++){
      int cg = w2i*64 + lane;               // global bf16 chunk in 4-row group
      int rl = (cg >= 288) ? 3 : (cg >= 192) ? 2 : (cg >= 96) ? 1 : 0;
      int c  = cg - rl*96;
      int row = wid*4 + rl;
      uint4 cc;
      cc.x=pack_bf2(st[w2i][0].x,st[w2i][0].y); cc.y=pack_bf2(st[w2i][0].z,st[w2i][0].w);
      cc.z=pack_bf2(st[w2i][1].x,st[w2i][1].y); cc.w=pack_bf2(st[w2i][1].z,st[w2i][1].w);
      *(uint4*)((char*)&B[row][0] + (c ^ (row&7))*16) = cc;
    }
  }
  __syncthreads();

  // ---- consume ----
  int q = lane >> 4;
  for (int m0 = 0; m0 < ne; m0 += 128){
    int rowid = m0 + wid*16 + (lane&15);
    int slotc = off0 + (rowid < ne ? rowid : ne-1);
    f32x4 acc0 = {0,0,0,0}, acc1 = {0,0,0,0};
    #pragma unroll
    for (int kh=0; kh<2; kh++){
      bf16x8 a[12];
      const ushort* ap = act + (size_t)slotc*IDIM + kh*384 + q*8;
      #pragma unroll
      for (int s=0;s<12;s++) a[s] = *(const bf16x8*)(ap + s*32);
      #pragma unroll
      for (int s=0;s<12;s++){
        int c = kh*48 + s*4 + q;
        {
          int row = lane&15;
          bf16x8 b = *(const bf16x8*)((const char*)&B[row][0] + (c ^ (row&7))*16);
          acc0 = __builtin_amdgcn_mfma_f32_16x16x32_bf16(a[s], b, acc0, 0,0,0);
        }
        {
          int row = 16 + (lane&15);
          bf16x8 b = *(const bf16x8*)((const char*)&B[row][0] + (c ^ (row&7))*16);
          acc1 = __builtin_amdgcn_mfma_f32_16x16x32_bf16(a[s], b, acc1, 0,0,0);
        }
      }
    }
    #pragma unroll
    for (int r=0;r<4;r++){
      int row = m0 + wid*16 + q*4 + r;
      if (row < ne){
        size_t base = (size_t)(off0+row)*HDIM + hbase + (lane&15);
        pout[base     ] = acc0[r];
        pout[base + 16] = acc1[r];
      }
    }
  }
}

// ---------------- combine ----------------
__global__ __launch_bounds__(256) void k_combine(const float* __restrict__ pout,
    const int* __restrict__ tk_slot, const float* __restrict__ wv,
    float* __restrict__ out){
  int t = blockIdx.x;
  int c = threadIdx.x;
  float a0=0,a1=0,a2=0,a3=0;
  #pragma unroll
  for (int k=0;k<TOPK;k++){
    int slot = tk_slot[t*TOPK+k];
    float w  = wv[t*TOPK+k];
    float4 v = *(const float4*)(pout + (size_t)slot*HDIM + c*4);
    a0 = fmaf(w, v.x, a0); a1 = fmaf(w, v.y, a1);
    a2 = fmaf(w, v.z, a2); a3 = fmaf(w, v.w, a3);
  }
  float4 o; o.x=a0; o.y=a1; o.z=a2; o.w=a3;
  *(float4*)(out + (size_t)t*HDIM + c*4) = o;
}

extern "C" void kernel_launch(void* const* d_in, const int* in_sizes, int n_in,
                              void* d_out, int out_size, void* d_ws, size_t ws_size,
                              hipStream_t stream){
  const float* x  = (const float*)d_in[0];
  const float* gw = (const float*)d_in[1];
  const float* w1 = (const float*)d_in[2];
  const float* w3 = (const float*)d_in[3];
  const float* w2 = (const float*)d_in[4];
  float* out = (float*)d_out;

  char* ws = (char*)d_ws;
  size_t off = 0;
  ushort* xb   = (ushort*)(ws + off); off += (size_t)T_TOK*HDIM*2;     // 4 MB
  ushort* gbuf = (ushort*)(ws + off); off += (size_t)NPAIR*IDIM*2;     // 12.6 MB
  ushort* ubuf = (ushort*)(ws + off); off += (size_t)NPAIR*IDIM*2;     // 12.6 MB
  ushort* act  = (ushort*)(ws + off); off += (size_t)NPAIR*IDIM*2;     // 12.6 MB
  float*  pout = (float*) (ws + off); off += (size_t)NPAIR*HDIM*4;     // 33.6 MB
  int* counts  = (int*)(ws + off); off += NEXP*4;
  int* cursor  = (int*)(ws + off); off += NEXP*4;
  int* offsets = (int*)(ws + off); off += (NEXP+1)*4;
  off = (off + 255) & ~(size_t)255;
  int*   ei      = (int*)  (ws + off); off += (size_t)NPAIR*4;
  float* wvp     = (float*)(ws + off); off += (size_t)NPAIR*4;
  int*   slot_tk = (int*)  (ws + off); off += (size_t)NPAIR*4;
  int*   tk_slot = (int*)  (ws + off); off += (size_t)NPAIR*4;

  hipMemsetAsync(counts, 0, 2*NEXP*4, stream);

  k_convert_x<<<T_TOK*HDIM/1024, 256, 0, stream>>>(x, xb);
  k_router<<<T_TOK/4, 256, 0, stream>>>(x, gw, ei, wvp, counts);
  k_offsets<<<1, 64, 0, stream>>>(counts, offsets);
  k_scatter<<<NPAIR/256, 256, 0, stream>>>(ei, offsets, cursor, slot_tk, tk_slot);
  k_gateup<<<1536, 512, 0, stream>>>(xb, w1, w3, offsets, slot_tk, gbuf, ubuf);
  k_actmul<<<1024, 256, 0, stream>>>(gbuf, ubuf, act);
  k_down<<<1024, 512, 0, stream>>>(act, w2, offsets, pout);
  k_combine<<<T_TOK, 256, 0, stream>>>(pout, tk_slot, wvp, out);
}